// Round 14
// baseline (825.636 us; speedup 1.0000x reference)
//
#include <hip/hip_runtime.h>

#define HID 128
#define G3  384   // 3*HID
#define TSTEPS 5
#define BSHIFT 9          // 512 nodes per bucket
#define BNODES (1 << BSHIFT)
#define MAXBUK 256        // supports N up to 128k
#define PART_EPB 8192     // edges per k_part block
#define DBUK 64           // degree-sort buckets

typedef unsigned int  uint;
typedef unsigned short ushort;

typedef float  f32x4  __attribute__((ext_vector_type(4)));
typedef __bf16 bf16x8 __attribute__((ext_vector_type(8)));

union B8u { uint4 u; bf16x8 b; ushort s[8]; };

static __device__ inline ushort f2bf(float f) {
  uint u = __float_as_uint(f);
  uint r = u + 0x7fffu + ((u >> 16) & 1u);   // RTN-even
  return (ushort)(r >> 16);
}
static __device__ inline float bf2f(ushort s) {
  return __uint_as_float(((uint)s) << 16);
}

// async global->LDS, 16B per lane, dest = wave-uniform base + lane*16
static __device__ __forceinline__ void gload_lds16(const void* g, void* l) {
  __builtin_amdgcn_global_load_lds(
      (const __attribute__((address_space(1))) uint*)g,
      (__attribute__((address_space(3))) uint*)l, 16, 0, 0);
}

// ---- once per call: W_comb = W_ih @ W_e (bf16), bvec = W_ih @ b_e, W_hh -> bf16
__global__ __launch_bounds__(128) void k_weights(
    const float* __restrict__ W_e, const float* __restrict__ b_e,
    const float* __restrict__ W_ih, const float* __restrict__ W_hh,
    ushort* __restrict__ Wcomb, ushort* __restrict__ Whh16, float* __restrict__ bvec,
    ushort* __restrict__ Wc0, ushort* __restrict__ Wh0)
{
  int j = blockIdx.x, t = threadIdx.x;
  if (j < G3) {
    __shared__ float row[HID];
    row[t] = W_ih[j * HID + t];
    __syncthreads();
    float acc = 0.f;
    for (int k = 0; k < HID; ++k) acc = fmaf(row[k], W_e[k * HID + t], acc);
    Wcomb[j * HID + t] = f2bf(acc);
    if (t == 0) {
      Wc0[j] = f2bf(acc);
      float b = 0.f;
      for (int k = 0; k < HID; ++k) b += row[k] * b_e[k];
      bvec[j] = b;
    }
  } else {
    int j2 = j - G3;
    Whh16[j2 * HID + t] = f2bf(W_hh[j2 * HID + t]);
    if (t == 0) Wh0[j2] = f2bf(W_hh[j2 * HID]);
  }
}

// ---- CSR build, stage 1: bucket histogram of dst (LDS-aggregated)
__global__ __launch_bounds__(256) void k_bh(const int* __restrict__ dst,
                                            int* __restrict__ bhist, int E) {
  __shared__ int lh[MAXBUK];
  int t = threadIdx.x;
  if (t < MAXBUK) lh[t] = 0;
  __syncthreads();
  for (int e = blockIdx.x * 256 + t; e < E; e += gridDim.x * 256)
    atomicAdd(&lh[dst[e] >> BSHIFT], 1);
  __syncthreads();
  if (t < MAXBUK && lh[t]) atomicAdd(&bhist[t], lh[t]);
}

// ---- stage 2: serial scan of <=256 bucket counts (trivial size)
__global__ __launch_bounds__(256) void k_bsc(const int* __restrict__ bhist,
                                             int* __restrict__ bbase,
                                             int* __restrict__ gcur,
                                             int* __restrict__ rowptr, int E, int N) {
  __shared__ int ls[MAXBUK];
  int t = threadIdx.x;
  ls[t] = bhist[t];
  __syncthreads();
  if (t == 0) {
    int run = 0;
    for (int i = 0; i < MAXBUK; ++i) {
      bbase[i] = run; gcur[i] = run; run += ls[i];
    }
    bbase[MAXBUK] = run;
    rowptr[N] = E;
  }
}

// ---- stage 3: partition packed (dl<<20)|src into bucket-grouped ebuf.
__global__ __launch_bounds__(256) void k_part(
    const int* __restrict__ src, const int* __restrict__ dst,
    int* __restrict__ gcur, uint* __restrict__ ebuf, int E) {
  __shared__ int lh[MAXBUK], lbase[MAXBUK], lcur[MAXBUK];
  int t = threadIdx.x;
  int base = blockIdx.x * PART_EPB;
  if (t < MAXBUK) lh[t] = 0;
  __syncthreads();
#pragma unroll 4
  for (int j = 0; j < PART_EPB / 256; ++j) {
    int e = base + j * 256 + t;
    if (e < E) atomicAdd(&lh[dst[e] >> BSHIFT], 1);
  }
  __syncthreads();
  if (t < MAXBUK) {
    lbase[t] = lh[t] ? atomicAdd(&gcur[t], lh[t]) : 0;
    lcur[t] = 0;
  }
  __syncthreads();
#pragma unroll 4
  for (int j = 0; j < PART_EPB / 256; ++j) {
    int e = base + j * 256 + t;
    if (e < E) {
      int d = dst[e];
      int b = d >> BSHIFT;
      int p = atomicAdd(&lcur[b], 1);
      ebuf[lbase[b] + p] = (uint)src[e] | ((uint)(d & (BNODES - 1)) << 20);
    }
  }
}

// ---- stage 4: one block per bucket: LDS hist -> scan -> rowptr/deg -> scatter
__global__ __launch_bounds__(256) void k_fill2(
    const uint* __restrict__ ebuf, const int* __restrict__ bbase,
    int* __restrict__ csrc, int* __restrict__ rowptr, int* __restrict__ deg, int N) {
  __shared__ int hcnt[BNODES];
  __shared__ int wls[4];
  int t = threadIdx.x;
  int b = blockIdx.x;
  int ebeg = bbase[b], eend = bbase[b + 1];
  for (int i = t; i < BNODES; i += 256) hcnt[i] = 0;
  __syncthreads();
  for (int e = ebeg + t; e < eend; e += 256)
    atomicAdd(&hcnt[ebuf[e] >> 20], 1);
  __syncthreads();
  const int PER = BNODES / 256;
  int lane = t & 63, wv = t >> 6;
  int x[PER]; int s = 0;
#pragma unroll
  for (int i = 0; i < PER; ++i) { x[i] = hcnt[PER * t + i]; s += x[i]; }
  int incl = s;
#pragma unroll
  for (int off = 1; off < 64; off <<= 1) {
    int u = __shfl_up(incl, off, 64);
    if (lane >= off) incl += u;
  }
  if (lane == 63) wls[wv] = incl;
  __syncthreads();
  int wbase = 0;
  for (int i = 0; i < wv; ++i) wbase += wls[i];
  int run = wbase + incl - s;
#pragma unroll
  for (int i = 0; i < PER; ++i) {
    int node = (b << BSHIFT) + PER * t + i;
    hcnt[PER * t + i] = run;
    if (node < N) { rowptr[node] = ebeg + run; deg[node] = x[i]; }
    run += x[i];
  }
  __syncthreads();
  for (int e = ebeg + t; e < eend; e += 256) {
    uint v = ebuf[e];
    int p = atomicAdd(&hcnt[v >> 20], 1);
    csrc[ebeg + p] = (int)(v & 0xFFFFFu);
  }
}

// ---- degree-sort: histogram -> scan -> scatter (LDS-aggregated, k_part
// pattern). Within-bucket order atomic-arbitrary; per-node computation is
// order-independent -> output bit-identical.
__global__ __launch_bounds__(256) void k_dhist(const int* __restrict__ deg,
                                               int* __restrict__ dhist, int N) {
  __shared__ int lh[DBUK];
  int t = threadIdx.x;
  if (t < DBUK) lh[t] = 0;
  __syncthreads();
  for (int v = blockIdx.x * 256 + t; v < N; v += gridDim.x * 256)
    atomicAdd(&lh[min(deg[v], DBUK - 1)], 1);
  __syncthreads();
  if (t < DBUK && lh[t]) atomicAdd(&dhist[t], lh[t]);
}

__global__ __launch_bounds__(64) void k_dscan(const int* __restrict__ dhist,
                                              int* __restrict__ dcur) {
  if (threadIdx.x == 0) {
    int run = 0;
    for (int i = 0; i < DBUK; ++i) { dcur[i] = run; run += dhist[i]; }
  }
}

__global__ __launch_bounds__(256) void k_dscatter(
    const int* __restrict__ deg, const int* __restrict__ rowptr,
    int* __restrict__ dcur, int* __restrict__ orig2,
    int* __restrict__ beg2, int* __restrict__ deg2s, int N) {
  __shared__ int lh[DBUK], lbase[DBUK], lcur[DBUK];
  int t = threadIdx.x;
  int v = blockIdx.x * 256 + t;
  if (t < DBUK) lh[t] = 0;
  __syncthreads();
  int d = 0, b = 0;
  bool valid = v < N;
  if (valid) {
    d = deg[v];
    b = min(d, DBUK - 1);
    atomicAdd(&lh[b], 1);
  }
  __syncthreads();
  if (t < DBUK) {
    lbase[t] = lh[t] ? atomicAdd(&dcur[t], lh[t]) : 0;
    lcur[t] = 0;
  }
  __syncthreads();
  if (valid) {
    int p = atomicAdd(&lcur[b], 1);
    int k = lbase[b] + p;
    orig2[k] = v;
    beg2[k] = rowptr[v];
    deg2s[k] = d;
  }
}

// ---- m16[v] = bf16(m[v]) — the only nonzero column of h at t=0
__global__ void k_minit(const float* __restrict__ m, ushort* __restrict__ m16, int N) {
  int v = blockIdx.x * 256 + threadIdx.x;
  if (v < N) m16[v] = f2bf(m[v]);
}

// ---- step-0 gather: h rows are [m,0,...,0] so only dim 0 needs summing.
__global__ __launch_bounds__(256) void k_gather0(
    const int* __restrict__ rowptr, const int* __restrict__ csrc,
    const ushort* __restrict__ m16, ushort* __restrict__ hsum0, int N)
{
  int v = blockIdx.x * 256 + threadIdx.x;
  if (v >= N) return;
  int beg = rowptr[v], end = rowptr[v + 1];
  float a0 = 0.f, a1 = 0.f, a2 = 0.f, a3 = 0.f;
  int e = beg;
  for (; e + 16 <= end; e += 16) {
    a0 += (bf2f(m16[csrc[e + 0]]) + bf2f(m16[csrc[e + 4]])) +
          (bf2f(m16[csrc[e + 8]]) + bf2f(m16[csrc[e + 12]]));
    a1 += (bf2f(m16[csrc[e + 1]]) + bf2f(m16[csrc[e + 5]])) +
          (bf2f(m16[csrc[e + 9]]) + bf2f(m16[csrc[e + 13]]));
    a2 += (bf2f(m16[csrc[e + 2]]) + bf2f(m16[csrc[e + 6]])) +
          (bf2f(m16[csrc[e + 10]]) + bf2f(m16[csrc[e + 14]]));
    a3 += (bf2f(m16[csrc[e + 3]]) + bf2f(m16[csrc[e + 7]])) +
          (bf2f(m16[csrc[e + 11]]) + bf2f(m16[csrc[e + 15]]));
  }
  for (; e < end; e += 4) {
    if (e + 0 < end) a0 += bf2f(m16[csrc[e + 0]]);
    if (e + 1 < end) a1 += bf2f(m16[csrc[e + 1]]);
    if (e + 2 < end) a2 += bf2f(m16[csrc[e + 2]]);
    if (e + 3 < end) a3 += bf2f(m16[csrc[e + 3]]);
  }
  hsum0[v] = f2bf((a0 + a1) + (a2 + a3));
}

// ---- step-0 GRU: both GEMMs are rank-1 (only k=0 of A/H nonzero).
__global__ __launch_bounds__(256) void k_gru0(
    const ushort* __restrict__ hsum0, const ushort* __restrict__ m16,
    const int* __restrict__ deg,
    const ushort* __restrict__ Wc0, const ushort* __restrict__ Wh0,
    const float* __restrict__ bvec, const float* __restrict__ b_ih,
    const float* __restrict__ b_hh, ushort* __restrict__ hbn, int N)
{
  int idx = blockIdx.x * 256 + threadIdx.x;
  if (idx >= N * HID) return;
  int n = idx >> 7, d = idx & (HID - 1);
  float s0 = bf2f(hsum0[n]);
  float h0 = bf2f(m16[n]);
  float degf = (float)deg[n];
  float acc0 = s0 * bf2f(Wc0[d]);
  float acc1 = s0 * bf2f(Wc0[d + 128]);
  float acc2 = s0 * bf2f(Wc0[d + 256]);
  float acc3 = h0 * bf2f(Wh0[d]);
  float acc4 = h0 * bf2f(Wh0[d + 128]);
  float acc5 = h0 * bf2f(Wh0[d + 256]);
  float hold = (d == 0) ? h0 : 0.f;
  float ir = acc0 + degf * bvec[d] + b_ih[d];
  float iz = acc1 + degf * bvec[d + 128] + b_ih[d + 128];
  float in_ = acc2 + degf * bvec[d + 256] + b_ih[d + 256];
  float hr = acc3 + b_hh[d];
  float hz = acc4 + b_hh[d + 128];
  float hn = acc5 + b_hh[d + 256];
  float r = __builtin_amdgcn_rcpf(1.f + __expf(-(ir + hr)));
  float z = __builtin_amdgcn_rcpf(1.f + __expf(-(iz + hz)));
  float x2 = in_ + r * hn;
  float e2 = __expf(2.f * x2);
  float nv = 1.f - 2.f * __builtin_amdgcn_rcpf(e2 + 1.f);   // tanh
  float hv = (1.f - z) * nv + z * hold;
  hbn[idx] = f2bf(hv);
}

// ---- fallback accumulate core (cnt > 31: rare with sort; R12 semantics)
static __device__ __forceinline__ void accum_range(
    const ushort* __restrict__ hb, const int* __restrict__ csrc,
    int beg, int end, int g, int i, float acc[8])
{
  int e = beg;
  for (; e + 16 <= end; e += 16) {
    int s0 = csrc[e + g];
    int s1 = csrc[e + 4 + g];
    int s2 = csrc[e + 8 + g];
    int s3 = csrc[e + 12 + g];
    B8u w0; w0.u = *(const uint4*)(hb + (size_t)s0 * HID + i * 8);
    B8u w1; w1.u = *(const uint4*)(hb + (size_t)s1 * HID + i * 8);
    B8u w2; w2.u = *(const uint4*)(hb + (size_t)s2 * HID + i * 8);
    B8u w3; w3.u = *(const uint4*)(hb + (size_t)s3 * HID + i * 8);
#pragma unroll
    for (int j = 0; j < 8; ++j)
      acc[j] += (bf2f(w0.s[j]) + bf2f(w1.s[j])) + (bf2f(w2.s[j]) + bf2f(w3.s[j]));
  }
  int rem = end - e;
  if (rem > 0) {
    int t0 = (g < rem)      ? csrc[e + g]      : -1;
    int t1 = (4 + g < rem)  ? csrc[e + 4 + g]  : -1;
    int t2 = (8 + g < rem)  ? csrc[e + 8 + g]  : -1;
    int t3 = (12 + g < rem) ? csrc[e + 12 + g] : -1;
    B8u r0, r1, r2, r3;
    if (t0 >= 0) r0.u = *(const uint4*)(hb + (size_t)t0 * HID + i * 8);
    if (t1 >= 0) r1.u = *(const uint4*)(hb + (size_t)t1 * HID + i * 8);
    if (t2 >= 0) r2.u = *(const uint4*)(hb + (size_t)t2 * HID + i * 8);
    if (t3 >= 0) r3.u = *(const uint4*)(hb + (size_t)t3 * HID + i * 8);
    if (t0 >= 0) {
#pragma unroll
      for (int j = 0; j < 8; ++j) acc[j] += bf2f(r0.s[j]);
    }
    if (t1 >= 0) {
#pragma unroll
      for (int j = 0; j < 8; ++j) acc[j] += bf2f(r1.s[j]);
    }
    if (t2 >= 0) {
#pragma unroll
      for (int j = 0; j < 8; ++j) acc[j] += bf2f(r2.s[j]);
    }
    if (t3 >= 0) {
#pragma unroll
      for (int j = 0; j < 8; ++j) acc[j] += bf2f(r3.s[j]);
    }
  }
}

// ---- full inline gather for one SORTED strip (prologue only; R12 verbatim)
static __device__ __forceinline__ void gather_strip_sorted(
    const int* __restrict__ beg2, const int* __restrict__ deg2s,
    const int* __restrict__ orig2, const int* __restrict__ csrc,
    const ushort* __restrict__ hb,
    int strip, int w, int lane, int N,
    ushort dstS[16][128], ushort dstH[16][128], int* dstDeg, int* dstOrig)
{
  int k = strip * 16 + w;
  if (k >= N) return;
  int g = lane >> 4;
  int i = lane & 15;
  int orig = orig2[k];
  int beg = beg2[k];
  int cnt = deg2s[k];
  if (g == 1)
    *(uint4*)(&dstH[w][(i ^ (w & 7)) * 8]) =
        *(const uint4*)(hb + (size_t)orig * HID + i * 8);
  if (lane == 0) dstOrig[w] = orig;
  if (lane == 32) dstDeg[w] = cnt;
  float acc[8] = {0.f, 0.f, 0.f, 0.f, 0.f, 0.f, 0.f, 0.f};
  accum_range(hb, csrc, beg, beg + cnt, g, i, acc);
#pragma unroll
  for (int j = 0; j < 8; ++j) {
    acc[j] += __shfl_xor(acc[j], 16, 64);
    acc[j] += __shfl_xor(acc[j], 32, 64);
  }
  if (g == 0) {
    uint4 ov;
    ov.x = ((uint)f2bf(acc[1]) << 16) | (uint)f2bf(acc[0]);
    ov.y = ((uint)f2bf(acc[3]) << 16) | (uint)f2bf(acc[2]);
    ov.z = ((uint)f2bf(acc[5]) << 16) | (uint)f2bf(acc[4]);
    ov.w = ((uint)f2bf(acc[7]) << 16) | (uint)f2bf(acc[6]);
    *(uint4*)(&dstS[w][(i ^ (w & 7)) * 8]) = ov;
  }
}

// ==== k_fused v7: R12 skeleton (2 barriers, single S, 3-parity AT) with the
// next strip's ROW loads issued as global_load_lds in phase A (zero VGPR for
// row data) and consumed in phase B2 after the raw barrier(a)+MFMA+S-writes
// have covered the L2/HBM round-trip. Chunks 0-4 (edges<20) via LDS; edges
// 20-31 via 3 prefetched-idx reg loads; cnt>31 -> accum_range fallback.
// Accumulation order == accum_range exactly -> bit-identical output.
// AT[nxt] writes moved to B2 are still before barrier(b); all readers of
// AT[nxt] run after barrier(b) -> same safety as R12.
__global__ __launch_bounds__(1024, 4) void k_fused(
    const int* __restrict__ beg2, const int* __restrict__ deg2s,
    const int* __restrict__ orig2, const int* __restrict__ csrc,
    const ushort* __restrict__ hbc, ushort* __restrict__ hbn,
    const ushort* __restrict__ Wcomb, const ushort* __restrict__ Whh16,
    const float* __restrict__ bvec, const float* __restrict__ b_ih,
    const float* __restrict__ b_hh, int N)
{
  __shared__ float S[6][16][132];        // 50688 B
  __shared__ ushort AT[3][2][16][128];   // 24576 B
  __shared__ int degT[3][16];
  __shared__ int origT[3][16];
  __shared__ ushort STG[16][5][512];     // 81920 B: per-wave 5 chunks x 4 rows
  const int tid = threadIdx.x;
  const int w = tid >> 6;
  const int lane = tid & 63;
  const int quad = lane >> 4, l16 = lane & 15;
  const int gm = w >> 3;
  const int gw = w & 7;
  const int d0 = gw * 16;

  const ushort* Wmat = gm ? Whh16 : Wcomb;
  B8u bfr[3][4];
#pragma unroll
  for (int g = 0; g < 3; ++g)
#pragma unroll
    for (int kc = 0; kc < 4; ++kc) {
      int j = (d0 + g * 128 + l16) * HID + kc * 32 + quad * 8;
      bfr[g][kc].u = *(const uint4*)(Wmat + j);
    }

  const int ecol = tid & 127, erow0 = tid >> 7;
  const float bir = b_ih[ecol], biz = b_ih[ecol + 128], bin_ = b_ih[ecol + 256];
  const float bhr = b_hh[ecol], bhz = b_hh[ecol + 128], bhn = b_hh[ecol + 256];
  const float vr = bvec[ecol], vz = bvec[ecol + 128], vn = bvec[ecol + 256];

  const int nstrip = N >> 4;
  const int G = (int)gridDim.x;
  int s = blockIdx.x;
  if (s >= nstrip) return;

  gather_strip_sorted(beg2, deg2s, orig2, csrc, hbc, s, w, lane, N,
                      AT[0][0], AT[0][1], degT[0], origT[0]);
  asm volatile("s_waitcnt lgkmcnt(0)" ::: "memory");
  __builtin_amdgcn_sched_barrier(0);
  __builtin_amdgcn_s_barrier();

  int cur = 0;
  while (true) {
    int ns = s + G;
    bool more = ns < nstrip;
    int nxt = (cur == 2) ? 0 : cur + 1;
    int cntP = 0, begP = 0, i5 = -1, i6 = -1, i7 = -1;
    uint4 hrow = make_uint4(0, 0, 0, 0);
    if (more) {
      // ---- phase A: meta + issue next strip's row loads direct-to-LDS
      int k2 = ns * 16 + w;
      int orig = orig2[k2];
      begP = beg2[k2];
      cntP = deg2s[k2];
      if (lane == 0) origT[nxt][w] = orig;
      if (lane == 32) degT[nxt][w] = cntP;
      if (quad == 1) hrow = *(const uint4*)(hbc + (size_t)orig * HID + l16 * 8);
      if (cntP <= 31) {
#pragma unroll
        for (int j = 0; j < 5; ++j)
          if (4 * j + quad < cntP) {
            int ix = csrc[begP + 4 * j + quad];
            gload_lds16(hbc + (size_t)ix * HID + l16 * 8, &STG[w][j][0]);
          }
        i5 = (20 + quad < cntP) ? csrc[begP + 20 + quad] : -1;
        i6 = (24 + quad < cntP) ? csrc[begP + 24 + quad] : -1;
        i7 = (28 + quad < cntP) ? csrc[begP + 28 + quad] : -1;
      }
    }
    // ---- phase B: GEMM on AT[cur]; row loads fly across barrier(a)
    B8u af[4];
#pragma unroll
    for (int kc = 0; kc < 4; ++kc)
      af[kc].u = *(const uint4*)(&AT[cur][gm][l16][(((quad + 4 * kc) ^ (l16 & 7)) * 8)]);
    f32x4 acc3[3] = {};
#pragma unroll
    for (int kc = 0; kc < 4; ++kc)
#pragma unroll
      for (int g = 0; g < 3; ++g)
        acc3[g] = __builtin_amdgcn_mfma_f32_16x16x32_bf16(af[kc].b, bfr[g][kc].b, acc3[g], 0, 0, 0);
    __builtin_amdgcn_s_barrier();          // (a) — no vmcnt drain
#pragma unroll
    for (int g = 0; g < 3; ++g)
#pragma unroll
      for (int rg = 0; rg < 4; ++rg)
        S[gm * 3 + g][quad * 4 + rg][d0 + l16] = acc3[g][rg];
    // ---- phase B2: finish gather for ns from STG (rows landed under GEMM)
    if (more) {
      float acc[8] = {0.f, 0.f, 0.f, 0.f, 0.f, 0.f, 0.f, 0.f};
      if (cntP <= 31) {
        asm volatile("s_waitcnt vmcnt(0)" ::: "memory");
        __builtin_amdgcn_sched_barrier(0);
        if (cntP >= 16) {
          B8u c0, c1, c2, c3;
          c0.u = *(const uint4*)&STG[w][0][lane * 8];
          c1.u = *(const uint4*)&STG[w][1][lane * 8];
          c2.u = *(const uint4*)&STG[w][2][lane * 8];
          c3.u = *(const uint4*)&STG[w][3][lane * 8];
#pragma unroll
          for (int j = 0; j < 8; ++j)
            acc[j] += (bf2f(c0.s[j]) + bf2f(c1.s[j])) + (bf2f(c2.s[j]) + bf2f(c3.s[j]));
        } else {
#pragma unroll
          for (int jj = 0; jj < 4; ++jj)
            if (4 * jj + quad < cntP) {
              B8u cv; cv.u = *(const uint4*)&STG[w][jj][lane * 8];
#pragma unroll
              for (int j = 0; j < 8; ++j) acc[j] += bf2f(cv.s[j]);
            }
        }
        if (16 + quad < cntP) {
          B8u c4; c4.u = *(const uint4*)&STG[w][4][lane * 8];
#pragma unroll
          for (int j = 0; j < 8; ++j) acc[j] += bf2f(c4.s[j]);
        }
        if (i5 >= 0) {
          B8u rv; rv.u = *(const uint4*)(hbc + (size_t)i5 * HID + l16 * 8);
#pragma unroll
          for (int j = 0; j < 8; ++j) acc[j] += bf2f(rv.s[j]);
        }
        if (i6 >= 0) {
          B8u rv; rv.u = *(const uint4*)(hbc + (size_t)i6 * HID + l16 * 8);
#pragma unroll
          for (int j = 0; j < 8; ++j) acc[j] += bf2f(rv.s[j]);
        }
        if (i7 >= 0) {
          B8u rv; rv.u = *(const uint4*)(hbc + (size_t)i7 * HID + l16 * 8);
#pragma unroll
          for (int j = 0; j < 8; ++j) acc[j] += bf2f(rv.s[j]);
        }
      } else {
        accum_range(hbc, csrc, begP, begP + cntP, quad, l16, acc);
      }
#pragma unroll
      for (int j = 0; j < 8; ++j) {
        acc[j] += __shfl_xor(acc[j], 16, 64);
        acc[j] += __shfl_xor(acc[j], 32, 64);
      }
      if (quad == 0) {
        uint4 ov;
        ov.x = ((uint)f2bf(acc[1]) << 16) | (uint)f2bf(acc[0]);
        ov.y = ((uint)f2bf(acc[3]) << 16) | (uint)f2bf(acc[2]);
        ov.z = ((uint)f2bf(acc[5]) << 16) | (uint)f2bf(acc[4]);
        ov.w = ((uint)f2bf(acc[7]) << 16) | (uint)f2bf(acc[6]);
        *(uint4*)(&AT[nxt][0][w][(l16 ^ (w & 7)) * 8]) = ov;
      }
      if (quad == 1) *(uint4*)(&AT[nxt][1][w][(l16 ^ (w & 7)) * 8]) = hrow;
    }
    // drain own LDS ops (S + AT writes + STG reads), leave vmcnt in flight
    asm volatile("s_waitcnt lgkmcnt(0)" ::: "memory");
    __builtin_amdgcn_sched_barrier(0);
    __builtin_amdgcn_s_barrier();          // (b)
    int n0 = s << 4;
#pragma unroll
    for (int k = 0; k < 2; ++k) {
      int row = erow0 + 8 * k;
      float dgf = (float)degT[cur][row];
      int og = origT[cur][row];
      int sc = (((ecol >> 3) ^ (row & 7)) * 8) + (ecol & 7);
      float hold = bf2f(AT[cur][1][row][sc]);
      float ir  = S[0][row][ecol] + dgf * vr + bir;
      float iz  = S[1][row][ecol] + dgf * vz + biz;
      float in_ = S[2][row][ecol] + dgf * vn + bin_;
      float hr  = S[3][row][ecol] + bhr;
      float hz  = S[4][row][ecol] + bhz;
      float hn  = S[5][row][ecol] + bhn;
      float r = __builtin_amdgcn_rcpf(1.f + __expf(-(ir + hr)));
      float z = __builtin_amdgcn_rcpf(1.f + __expf(-(iz + hz)));
      float x2 = in_ + r * hn;
      float e2 = __expf(2.f * x2);
      float nv = 1.f - 2.f * __builtin_amdgcn_rcpf(e2 + 1.f);   // tanh
      float hv = (1.f - z) * nv + z * hold;
      if (n0 + row < N)
        hbn[(size_t)og * HID + ecol] = f2bf(hv);
    }
    if (!more) break;
    s = ns; cur = nxt;
  }
}

// ---- per-graph counts from SORTED gid: binary search, no atomics
__global__ __launch_bounds__(64) void k_bounds(const int* __restrict__ gid,
                                               int* __restrict__ cnt, int N, int G) {
  int g = threadIdx.x;
  if (g >= G) return;
  int lo = 0, hi = N;
  while (lo < hi) { int mid = (lo + hi) >> 1; if (gid[mid] < g) lo = mid + 1; else hi = mid; }
  int lb0 = lo;
  lo = 0; hi = N;
  int g1 = g + 1;
  while (lo < hi) { int mid = (lo + hi) >> 1; if (gid[mid] < g1) lo = mid + 1; else hi = mid; }
  cnt[g] = lo - lb0;
}

// ---- pooling: graph_ids sorted -> run-length accumulate, few atomics
#define POOL_CHUNK 96
__global__ __launch_bounds__(128) void k_pool(const ushort* __restrict__ hb,
                                              const int* __restrict__ gid,
                                              float* __restrict__ hg, int N) {
  int d = threadIdx.x;
  int start = blockIdx.x * POOL_CHUNK;
  if (start >= N) return;
  int end = min(start + POOL_CHUNK, N);
  float acc = 0.f;
  int g = gid[start];
  for (int n = start; n < end; ++n) {
    int gn = gid[n];
    if (gn != g) { unsafeAtomicAdd(&hg[g * HID + d], acc); acc = 0.f; g = gn; }
    acc += fmaxf(bf2f(hb[(size_t)n * HID + d]), 0.f);   // relu
  }
  unsafeAtomicAdd(&hg[g * HID + d], acc);
}

__global__ __launch_bounds__(640) void k_cls(const float* __restrict__ hg,
                                             const int* __restrict__ cnt,
                                             const float* __restrict__ Wc,
                                             const float* __restrict__ bc,
                                             float* __restrict__ out, int G) {
  int t = threadIdx.x;
  if (t >= G * 10) return;
  int g = t / 10, c = t % 10;
  float inv = 1.f / fmaxf((float)cnt[g], 1.f);
  float acc = 0.f;
  for (int d = 0; d < HID; ++d) acc = fmaf(hg[g * HID + d], Wc[c * HID + d], acc);
  out[t] = acc * inv + bc[c];
}

extern "C" void kernel_launch(void* const* d_in, const int* in_sizes, int n_in,
                              void* d_out, int out_size, void* d_ws, size_t ws_size,
                              hipStream_t stream) {
  const int N = in_sizes[0];
  const int E = in_sizes[9];
  const float* m    = (const float*)d_in[0];
  const float* W_e  = (const float*)d_in[1];
  const float* b_e  = (const float*)d_in[2];
  const float* W_ih = (const float*)d_in[3];
  const float* b_ih = (const float*)d_in[4];
  const float* W_hh = (const float*)d_in[5];
  const float* b_hh = (const float*)d_in[6];
  const float* W_cls = (const float*)d_in[7];
  const float* b_cls = (const float*)d_in[8];
  const int* src = (const int*)d_in[9];
  const int* dst = (const int*)d_in[10];
  const int* gid = (const int*)d_in[11];
  const int G = out_size / 10;
  float* out = (float*)d_out;

  size_t off = 0;
  auto alloc = [&](size_t b) {
    char* p = (char*)d_ws + off;
    off += (b + 255) & ~(size_t)255;
    return (void*)p;
  };
  ushort* hb0    = (ushort*)alloc((size_t)N * HID * 2);
  ushort* hb1    = (ushort*)alloc((size_t)N * HID * 2);
  int*    deg    = (int*)   alloc((size_t)N * 4);
  int*    rowptr = (int*)   alloc((size_t)(N + 1) * 4);
  int*    csrc   = (int*)   alloc((size_t)E * 4);
  uint*   ebuf   = (uint*)  alloc((size_t)E * 4);
  int*    bhist  = (int*)   alloc((size_t)MAXBUK * 4);
  int*    bbase  = (int*)   alloc((size_t)(MAXBUK + 1) * 4);
  int*    gcur   = (int*)   alloc((size_t)MAXBUK * 4);
  ushort* Wcomb  = (ushort*)alloc((size_t)G3 * HID * 2);
  ushort* Whh16  = (ushort*)alloc((size_t)G3 * HID * 2);
  float*  bvec   = (float*) alloc((size_t)G3 * 4);
  float*  hg     = (float*) alloc((size_t)G * HID * 4);
  int*    cnt    = (int*)   alloc((size_t)G * 4);
  ushort* m16    = (ushort*)alloc((size_t)N * 2);
  ushort* hsum0  = (ushort*)alloc((size_t)N * 2);
  ushort* Wc0    = (ushort*)alloc((size_t)G3 * 2);
  ushort* Wh0    = (ushort*)alloc((size_t)G3 * 2);
  int*    dhist  = (int*)   alloc((size_t)DBUK * 4);
  int*    dcur   = (int*)   alloc((size_t)DBUK * 4);
  int*    orig2  = (int*)   alloc((size_t)N * 4);
  int*    beg2   = (int*)   alloc((size_t)N * 4);
  int*    deg2s  = (int*)   alloc((size_t)N * 4);
  if (off > ws_size) return;   // workspace too small -> visible failure

  const int NBUK = (N + BNODES - 1) >> BSHIFT;   // 196 at N=100k (<= MAXBUK)

  k_weights<<<2 * G3, HID, 0, stream>>>(W_e, b_e, W_ih, W_hh, Wcomb, Whh16, bvec, Wc0, Wh0);
  k_minit<<<(N + 255) / 256, 256, 0, stream>>>(m, m16, N);
  hipMemsetAsync(bhist, 0, (size_t)MAXBUK * 4, stream);
  k_bh<<<256, 256, 0, stream>>>(dst, bhist, E);
  k_bsc<<<1, MAXBUK, 0, stream>>>(bhist, bbase, gcur, rowptr, E, N);
  k_part<<<(E + PART_EPB - 1) / PART_EPB, 256, 0, stream>>>(src, dst, gcur, ebuf, E);
  k_fill2<<<NBUK, 256, 0, stream>>>(ebuf, bbase, csrc, rowptr, deg, N);

  // ---- degree-sort the node processing order (one-time, LDS-aggregated)
  hipMemsetAsync(dhist, 0, (size_t)DBUK * 4, stream);
  k_dhist<<<64, 256, 0, stream>>>(deg, dhist, N);
  k_dscan<<<1, 64, 0, stream>>>(dhist, dcur);
  k_dscatter<<<(N + 255) / 256, 256, 0, stream>>>(deg, rowptr, dcur, orig2, beg2, deg2s, N);

  // ---- step 0: h = [m,0,...,0] is rank-1 -> scalar gather + rank-1 GRU
  k_gather0<<<(N + 255) / 256, 256, 0, stream>>>(rowptr, csrc, m16, hsum0, N);
  k_gru0<<<(N * HID + 255) / 256, 256, 0, stream>>>(hsum0, m16, deg, Wc0, Wh0,
                                                    bvec, b_ih, b_hh, hb1, N);

  ushort* hbc = hb1;
  ushort* hbn = hb0;
  const int nstrip = N >> 4;
  const int fuse_blocks = nstrip < 256 ? nstrip : 256;   // 1 block/CU
  for (int s = 1; s < TSTEPS; ++s) {
    k_fused<<<fuse_blocks, 1024, 0, stream>>>(beg2, deg2s, orig2, csrc, hbc, hbn,
                                              Wcomb, Whh16, bvec, b_ih, b_hh, N);
    ushort* t = hbc; hbc = hbn; hbn = t;
  }

  hipMemsetAsync(hg, 0, (size_t)G * HID * 4, stream);
  k_bounds<<<1, 64, 0, stream>>>(gid, cnt, N, G);
  k_pool<<<(N + POOL_CHUNK - 1) / POOL_CHUNK, HID, 0, stream>>>(hbc, gid, hg, N);
  k_cls<<<1, 640, 0, stream>>>(hg, cnt, W_cls, b_cls, out, G);
}

// Round 15
// 762.382 us; speedup vs baseline: 1.0830x; 1.0830x over previous
//
#include <hip/hip_runtime.h>

#define HID 128
#define G3  384   // 3*HID
#define TSTEPS 5
#define BSHIFT 9          // 512 nodes per bucket
#define BNODES (1 << BSHIFT)
#define MAXBUK 256        // supports N up to 128k
#define PART_EPB 8192     // edges per k_part block
#define DBUK 64           // degree-sort buckets

typedef unsigned int  uint;
typedef unsigned short ushort;

typedef float  f32x4  __attribute__((ext_vector_type(4)));
typedef __bf16 bf16x8 __attribute__((ext_vector_type(8)));

union B8u { uint4 u; bf16x8 b; ushort s[8]; };

static __device__ inline ushort f2bf(float f) {
  uint u = __float_as_uint(f);
  uint r = u + 0x7fffu + ((u >> 16) & 1u);   // RTN-even
  return (ushort)(r >> 16);
}
static __device__ inline float bf2f(ushort s) {
  return __uint_as_float(((uint)s) << 16);
}

// ---- once per call: W_comb = W_ih @ W_e (bf16), bvec = W_ih @ b_e, W_hh -> bf16
__global__ __launch_bounds__(128) void k_weights(
    const float* __restrict__ W_e, const float* __restrict__ b_e,
    const float* __restrict__ W_ih, const float* __restrict__ W_hh,
    ushort* __restrict__ Wcomb, ushort* __restrict__ Whh16, float* __restrict__ bvec,
    ushort* __restrict__ Wc0, ushort* __restrict__ Wh0)
{
  int j = blockIdx.x, t = threadIdx.x;
  if (j < G3) {
    __shared__ float row[HID];
    row[t] = W_ih[j * HID + t];
    __syncthreads();
    float acc = 0.f;
    for (int k = 0; k < HID; ++k) acc = fmaf(row[k], W_e[k * HID + t], acc);
    Wcomb[j * HID + t] = f2bf(acc);
    if (t == 0) {
      Wc0[j] = f2bf(acc);
      float b = 0.f;
      for (int k = 0; k < HID; ++k) b += row[k] * b_e[k];
      bvec[j] = b;
    }
  } else {
    int j2 = j - G3;
    Whh16[j2 * HID + t] = f2bf(W_hh[j2 * HID + t]);
    if (t == 0) Wh0[j2] = f2bf(W_hh[j2 * HID]);
  }
}

// ---- CSR build, stage 1: bucket histogram of dst (LDS-aggregated)
__global__ __launch_bounds__(256) void k_bh(const int* __restrict__ dst,
                                            int* __restrict__ bhist, int E) {
  __shared__ int lh[MAXBUK];
  int t = threadIdx.x;
  if (t < MAXBUK) lh[t] = 0;
  __syncthreads();
  for (int e = blockIdx.x * 256 + t; e < E; e += gridDim.x * 256)
    atomicAdd(&lh[dst[e] >> BSHIFT], 1);
  __syncthreads();
  if (t < MAXBUK && lh[t]) atomicAdd(&bhist[t], lh[t]);
}

// ---- stage 2: serial scan of <=256 bucket counts (trivial size)
__global__ __launch_bounds__(256) void k_bsc(const int* __restrict__ bhist,
                                             int* __restrict__ bbase,
                                             int* __restrict__ gcur,
                                             int* __restrict__ rowptr, int E, int N) {
  __shared__ int ls[MAXBUK];
  int t = threadIdx.x;
  ls[t] = bhist[t];
  __syncthreads();
  if (t == 0) {
    int run = 0;
    for (int i = 0; i < MAXBUK; ++i) {
      bbase[i] = run; gcur[i] = run; run += ls[i];
    }
    bbase[MAXBUK] = run;
    rowptr[N] = E;
  }
}

// ---- stage 3: partition packed (dl<<20)|src into bucket-grouped ebuf.
__global__ __launch_bounds__(256) void k_part(
    const int* __restrict__ src, const int* __restrict__ dst,
    int* __restrict__ gcur, uint* __restrict__ ebuf, int E) {
  __shared__ int lh[MAXBUK], lbase[MAXBUK], lcur[MAXBUK];
  int t = threadIdx.x;
  int base = blockIdx.x * PART_EPB;
  if (t < MAXBUK) lh[t] = 0;
  __syncthreads();
#pragma unroll 4
  for (int j = 0; j < PART_EPB / 256; ++j) {
    int e = base + j * 256 + t;
    if (e < E) atomicAdd(&lh[dst[e] >> BSHIFT], 1);
  }
  __syncthreads();
  if (t < MAXBUK) {
    lbase[t] = lh[t] ? atomicAdd(&gcur[t], lh[t]) : 0;
    lcur[t] = 0;
  }
  __syncthreads();
#pragma unroll 4
  for (int j = 0; j < PART_EPB / 256; ++j) {
    int e = base + j * 256 + t;
    if (e < E) {
      int d = dst[e];
      int b = d >> BSHIFT;
      int p = atomicAdd(&lcur[b], 1);
      ebuf[lbase[b] + p] = (uint)src[e] | ((uint)(d & (BNODES - 1)) << 20);
    }
  }
}

// ---- stage 4: one block per bucket: LDS hist -> scan -> rowptr/deg -> scatter
__global__ __launch_bounds__(256) void k_fill2(
    const uint* __restrict__ ebuf, const int* __restrict__ bbase,
    int* __restrict__ csrc, int* __restrict__ rowptr, int* __restrict__ deg, int N) {
  __shared__ int hcnt[BNODES];
  __shared__ int wls[4];
  int t = threadIdx.x;
  int b = blockIdx.x;
  int ebeg = bbase[b], eend = bbase[b + 1];
  for (int i = t; i < BNODES; i += 256) hcnt[i] = 0;
  __syncthreads();
  for (int e = ebeg + t; e < eend; e += 256)
    atomicAdd(&hcnt[ebuf[e] >> 20], 1);
  __syncthreads();
  const int PER = BNODES / 256;
  int lane = t & 63, wv = t >> 6;
  int x[PER]; int s = 0;
#pragma unroll
  for (int i = 0; i < PER; ++i) { x[i] = hcnt[PER * t + i]; s += x[i]; }
  int incl = s;
#pragma unroll
  for (int off = 1; off < 64; off <<= 1) {
    int u = __shfl_up(incl, off, 64);
    if (lane >= off) incl += u;
  }
  if (lane == 63) wls[wv] = incl;
  __syncthreads();
  int wbase = 0;
  for (int i = 0; i < wv; ++i) wbase += wls[i];
  int run = wbase + incl - s;
#pragma unroll
  for (int i = 0; i < PER; ++i) {
    int node = (b << BSHIFT) + PER * t + i;
    hcnt[PER * t + i] = run;
    if (node < N) { rowptr[node] = ebeg + run; deg[node] = x[i]; }
    run += x[i];
  }
  __syncthreads();
  for (int e = ebeg + t; e < eend; e += 256) {
    uint v = ebuf[e];
    int p = atomicAdd(&hcnt[v >> 20], 1);
    csrc[ebeg + p] = (int)(v & 0xFFFFFu);
  }
}

// ---- degree-sort: histogram -> scan -> scatter (LDS-aggregated, k_part
// pattern). Within-bucket order atomic-arbitrary; per-node computation is
// order-independent -> output bit-identical.
__global__ __launch_bounds__(256) void k_dhist(const int* __restrict__ deg,
                                               int* __restrict__ dhist, int N) {
  __shared__ int lh[DBUK];
  int t = threadIdx.x;
  if (t < DBUK) lh[t] = 0;
  __syncthreads();
  for (int v = blockIdx.x * 256 + t; v < N; v += gridDim.x * 256)
    atomicAdd(&lh[min(deg[v], DBUK - 1)], 1);
  __syncthreads();
  if (t < DBUK && lh[t]) atomicAdd(&dhist[t], lh[t]);
}

__global__ __launch_bounds__(64) void k_dscan(const int* __restrict__ dhist,
                                              int* __restrict__ dcur) {
  if (threadIdx.x == 0) {
    int run = 0;
    for (int i = 0; i < DBUK; ++i) { dcur[i] = run; run += dhist[i]; }
  }
}

__global__ __launch_bounds__(256) void k_dscatter(
    const int* __restrict__ deg, const int* __restrict__ rowptr,
    int* __restrict__ dcur, int* __restrict__ orig2,
    int* __restrict__ beg2, int* __restrict__ deg2s, int N) {
  __shared__ int lh[DBUK], lbase[DBUK], lcur[DBUK];
  int t = threadIdx.x;
  int v = blockIdx.x * 256 + t;
  if (t < DBUK) lh[t] = 0;
  __syncthreads();
  int d = 0, b = 0;
  bool valid = v < N;
  if (valid) {
    d = deg[v];
    b = min(d, DBUK - 1);
    atomicAdd(&lh[b], 1);
  }
  __syncthreads();
  if (t < DBUK) {
    lbase[t] = lh[t] ? atomicAdd(&dcur[t], lh[t]) : 0;
    lcur[t] = 0;
  }
  __syncthreads();
  if (valid) {
    int p = atomicAdd(&lcur[b], 1);
    int k = lbase[b] + p;
    orig2[k] = v;
    beg2[k] = rowptr[v];
    deg2s[k] = d;
  }
}

// ---- m16[v] = bf16(m[v]) — the only nonzero column of h at t=0
__global__ void k_minit(const float* __restrict__ m, ushort* __restrict__ m16, int N) {
  int v = blockIdx.x * 256 + threadIdx.x;
  if (v < N) m16[v] = f2bf(m[v]);
}

// ---- step-0 gather: h rows are [m,0,...,0] so only dim 0 needs summing.
__global__ __launch_bounds__(256) void k_gather0(
    const int* __restrict__ rowptr, const int* __restrict__ csrc,
    const ushort* __restrict__ m16, ushort* __restrict__ hsum0, int N)
{
  int v = blockIdx.x * 256 + threadIdx.x;
  if (v >= N) return;
  int beg = rowptr[v], end = rowptr[v + 1];
  float a0 = 0.f, a1 = 0.f, a2 = 0.f, a3 = 0.f;
  int e = beg;
  for (; e + 16 <= end; e += 16) {
    a0 += (bf2f(m16[csrc[e + 0]]) + bf2f(m16[csrc[e + 4]])) +
          (bf2f(m16[csrc[e + 8]]) + bf2f(m16[csrc[e + 12]]));
    a1 += (bf2f(m16[csrc[e + 1]]) + bf2f(m16[csrc[e + 5]])) +
          (bf2f(m16[csrc[e + 9]]) + bf2f(m16[csrc[e + 13]]));
    a2 += (bf2f(m16[csrc[e + 2]]) + bf2f(m16[csrc[e + 6]])) +
          (bf2f(m16[csrc[e + 10]]) + bf2f(m16[csrc[e + 14]]));
    a3 += (bf2f(m16[csrc[e + 3]]) + bf2f(m16[csrc[e + 7]])) +
          (bf2f(m16[csrc[e + 11]]) + bf2f(m16[csrc[e + 15]]));
  }
  for (; e < end; e += 4) {
    if (e + 0 < end) a0 += bf2f(m16[csrc[e + 0]]);
    if (e + 1 < end) a1 += bf2f(m16[csrc[e + 1]]);
    if (e + 2 < end) a2 += bf2f(m16[csrc[e + 2]]);
    if (e + 3 < end) a3 += bf2f(m16[csrc[e + 3]]);
  }
  hsum0[v] = f2bf((a0 + a1) + (a2 + a3));
}

// ---- step-0 GRU: both GEMMs are rank-1 (only k=0 of A/H nonzero).
__global__ __launch_bounds__(256) void k_gru0(
    const ushort* __restrict__ hsum0, const ushort* __restrict__ m16,
    const int* __restrict__ deg,
    const ushort* __restrict__ Wc0, const ushort* __restrict__ Wh0,
    const float* __restrict__ bvec, const float* __restrict__ b_ih,
    const float* __restrict__ b_hh, ushort* __restrict__ hbn, int N)
{
  int idx = blockIdx.x * 256 + threadIdx.x;
  if (idx >= N * HID) return;
  int n = idx >> 7, d = idx & (HID - 1);
  float s0 = bf2f(hsum0[n]);
  float h0 = bf2f(m16[n]);
  float degf = (float)deg[n];
  float acc0 = s0 * bf2f(Wc0[d]);
  float acc1 = s0 * bf2f(Wc0[d + 128]);
  float acc2 = s0 * bf2f(Wc0[d + 256]);
  float acc3 = h0 * bf2f(Wh0[d]);
  float acc4 = h0 * bf2f(Wh0[d + 128]);
  float acc5 = h0 * bf2f(Wh0[d + 256]);
  float hold = (d == 0) ? h0 : 0.f;
  float ir = acc0 + degf * bvec[d] + b_ih[d];
  float iz = acc1 + degf * bvec[d + 128] + b_ih[d + 128];
  float in_ = acc2 + degf * bvec[d + 256] + b_ih[d + 256];
  float hr = acc3 + b_hh[d];
  float hz = acc4 + b_hh[d + 128];
  float hn = acc5 + b_hh[d + 256];
  float r = __builtin_amdgcn_rcpf(1.f + __expf(-(ir + hr)));
  float z = __builtin_amdgcn_rcpf(1.f + __expf(-(iz + hz)));
  float x2 = in_ + r * hn;
  float e2 = __expf(2.f * x2);
  float nv = 1.f - 2.f * __builtin_amdgcn_rcpf(e2 + 1.f);   // tanh
  float hv = (1.f - z) * nv + z * hold;
  hbn[idx] = f2bf(hv);
}

// ---- fallback accumulate core (cnt > 31: rare with sort)
static __device__ __forceinline__ void accum_range(
    const ushort* __restrict__ hb, const int* __restrict__ csrc,
    int beg, int end, int g, int i, float acc[8])
{
  int e = beg;
  for (; e + 16 <= end; e += 16) {
    int s0 = csrc[e + g];
    int s1 = csrc[e + 4 + g];
    int s2 = csrc[e + 8 + g];
    int s3 = csrc[e + 12 + g];
    B8u w0; w0.u = *(const uint4*)(hb + (size_t)s0 * HID + i * 8);
    B8u w1; w1.u = *(const uint4*)(hb + (size_t)s1 * HID + i * 8);
    B8u w2; w2.u = *(const uint4*)(hb + (size_t)s2 * HID + i * 8);
    B8u w3; w3.u = *(const uint4*)(hb + (size_t)s3 * HID + i * 8);
#pragma unroll
    for (int j = 0; j < 8; ++j)
      acc[j] += (bf2f(w0.s[j]) + bf2f(w1.s[j])) + (bf2f(w2.s[j]) + bf2f(w3.s[j]));
  }
  int rem = end - e;
  if (rem > 0) {
    int t0 = (g < rem)      ? csrc[e + g]      : -1;
    int t1 = (4 + g < rem)  ? csrc[e + 4 + g]  : -1;
    int t2 = (8 + g < rem)  ? csrc[e + 8 + g]  : -1;
    int t3 = (12 + g < rem) ? csrc[e + 12 + g] : -1;
    B8u r0, r1, r2, r3;
    if (t0 >= 0) r0.u = *(const uint4*)(hb + (size_t)t0 * HID + i * 8);
    if (t1 >= 0) r1.u = *(const uint4*)(hb + (size_t)t1 * HID + i * 8);
    if (t2 >= 0) r2.u = *(const uint4*)(hb + (size_t)t2 * HID + i * 8);
    if (t3 >= 0) r3.u = *(const uint4*)(hb + (size_t)t3 * HID + i * 8);
    if (t0 >= 0) {
#pragma unroll
      for (int j = 0; j < 8; ++j) acc[j] += bf2f(r0.s[j]);
    }
    if (t1 >= 0) {
#pragma unroll
      for (int j = 0; j < 8; ++j) acc[j] += bf2f(r1.s[j]);
    }
    if (t2 >= 0) {
#pragma unroll
      for (int j = 0; j < 8; ++j) acc[j] += bf2f(r2.s[j]);
    }
    if (t3 >= 0) {
#pragma unroll
      for (int j = 0; j < 8; ++j) acc[j] += bf2f(r3.s[j]);
    }
  }
}

// ---- gather one SORTED strip. For cnt<=31 (~99.9% of sorted slots) ALL
// csrc loads (main + tail) issue in ONE batch -> 3 serialized RTs instead
// of 4 (csrc-all -> rows-main -> rows-tail). Accumulation order preserved
// exactly (main tree, then t0..t3 singles) -> bit-identical.
static __device__ __forceinline__ void gather_strip_sorted(
    const int* __restrict__ beg2, const int* __restrict__ deg2s,
    const int* __restrict__ orig2, const int* __restrict__ csrc,
    const ushort* __restrict__ hb,
    int strip, int w, int lane, int N,
    ushort dstS[16][128], ushort dstH[16][128], int* dstDeg, int* dstOrig)
{
  int k = strip * 16 + w;
  if (k >= N) return;
  int g = lane >> 4;        // edge slot 0..3
  int i = lane & 15;        // 16B chunk of row
  int orig = orig2[k];
  int beg = beg2[k];
  int cnt = deg2s[k];
  if (g == 1)               // stage this node's h row (bit-identical copy)
    *(uint4*)(&dstH[w][(i ^ (w & 7)) * 8]) =
        *(const uint4*)(hb + (size_t)orig * HID + i * 8);
  if (lane == 0) dstOrig[w] = orig;
  if (lane == 32) dstDeg[w] = cnt;
  float acc[8] = {0.f, 0.f, 0.f, 0.f, 0.f, 0.f, 0.f, 0.f};
  if (cnt <= 31) {
    bool hm = cnt >= 16;
    int m0 = 0, m1 = 0, m2 = 0, m3 = 0;
    if (hm) {
      m0 = csrc[beg + g];
      m1 = csrc[beg + 4 + g];
      m2 = csrc[beg + 8 + g];
      m3 = csrc[beg + 12 + g];
    }
    int tb = hm ? beg + 16 : beg;
    int rem = hm ? cnt - 16 : cnt;
    int t0 = (g < rem)      ? csrc[tb + g]      : -1;
    int t1 = (4 + g < rem)  ? csrc[tb + 4 + g]  : -1;
    int t2 = (8 + g < rem)  ? csrc[tb + 8 + g]  : -1;
    int t3 = (12 + g < rem) ? csrc[tb + 12 + g] : -1;
    if (hm) {
      B8u w0, w1, w2, w3;
      w0.u = *(const uint4*)(hb + (size_t)m0 * HID + i * 8);
      w1.u = *(const uint4*)(hb + (size_t)m1 * HID + i * 8);
      w2.u = *(const uint4*)(hb + (size_t)m2 * HID + i * 8);
      w3.u = *(const uint4*)(hb + (size_t)m3 * HID + i * 8);
#pragma unroll
      for (int j = 0; j < 8; ++j)
        acc[j] += (bf2f(w0.s[j]) + bf2f(w1.s[j])) + (bf2f(w2.s[j]) + bf2f(w3.s[j]));
    }
    B8u r0, r1, r2, r3;
    if (t0 >= 0) r0.u = *(const uint4*)(hb + (size_t)t0 * HID + i * 8);
    if (t1 >= 0) r1.u = *(const uint4*)(hb + (size_t)t1 * HID + i * 8);
    if (t2 >= 0) r2.u = *(const uint4*)(hb + (size_t)t2 * HID + i * 8);
    if (t3 >= 0) r3.u = *(const uint4*)(hb + (size_t)t3 * HID + i * 8);
    if (t0 >= 0) {
#pragma unroll
      for (int j = 0; j < 8; ++j) acc[j] += bf2f(r0.s[j]);
    }
    if (t1 >= 0) {
#pragma unroll
      for (int j = 0; j < 8; ++j) acc[j] += bf2f(r1.s[j]);
    }
    if (t2 >= 0) {
#pragma unroll
      for (int j = 0; j < 8; ++j) acc[j] += bf2f(r2.s[j]);
    }
    if (t3 >= 0) {
#pragma unroll
      for (int j = 0; j < 8; ++j) acc[j] += bf2f(r3.s[j]);
    }
  } else {
    accum_range(hb, csrc, beg, beg + cnt, g, i, acc);
  }
#pragma unroll
  for (int j = 0; j < 8; ++j) {
    acc[j] += __shfl_xor(acc[j], 16, 64);
    acc[j] += __shfl_xor(acc[j], 32, 64);
  }
  if (g == 0) {
    uint4 ov;
    ov.x = ((uint)f2bf(acc[1]) << 16) | (uint)f2bf(acc[0]);
    ov.y = ((uint)f2bf(acc[3]) << 16) | (uint)f2bf(acc[2]);
    ov.z = ((uint)f2bf(acc[5]) << 16) | (uint)f2bf(acc[4]);
    ov.w = ((uint)f2bf(acc[7]) << 16) | (uint)f2bf(acc[6]);
    *(uint4*)(&dstS[w][(i ^ (w & 7)) * 8]) = ov;
  }
}

// ==== k_fused (R12, best verified: 126.3us/step, 752.9us total): gather +
// dual-GEMM + GRU per degree-sorted strip; 2 raw barriers, single S,
// 3-parity AT; epilogue writes hbn[orig] -> bit-identical output.
__global__ __launch_bounds__(1024, 4) void k_fused(
    const int* __restrict__ beg2, const int* __restrict__ deg2s,
    const int* __restrict__ orig2, const int* __restrict__ csrc,
    const ushort* __restrict__ hbc, ushort* __restrict__ hbn,
    const ushort* __restrict__ Wcomb, const ushort* __restrict__ Whh16,
    const float* __restrict__ bvec, const float* __restrict__ b_ih,
    const float* __restrict__ b_hh, int N)
{
  __shared__ float S[6][16][132];        // 50688 B, +4 pad
  __shared__ ushort AT[3][2][16][128];   // 24576 B: [parity][0=gathersum,1=hrow]
  __shared__ int degT[3][16];
  __shared__ int origT[3][16];
  const int tid = threadIdx.x;
  const int w = tid >> 6;
  const int lane = tid & 63;
  const int quad = lane >> 4, l16 = lane & 15;
  const int gm = w >> 3;            // 0: W-path (gathersum x Wcomb), 1: H-path
  const int gw = w & 7;
  const int d0 = gw * 16;

  const ushort* Wmat = gm ? Whh16 : Wcomb;
  B8u bfr[3][4];
#pragma unroll
  for (int g = 0; g < 3; ++g)
#pragma unroll
    for (int kc = 0; kc < 4; ++kc) {
      int j = (d0 + g * 128 + l16) * HID + kc * 32 + quad * 8;
      bfr[g][kc].u = *(const uint4*)(Wmat + j);
    }

  const int ecol = tid & 127, erow0 = tid >> 7;
  const float bir = b_ih[ecol], biz = b_ih[ecol + 128], bin_ = b_ih[ecol + 256];
  const float bhr = b_hh[ecol], bhz = b_hh[ecol + 128], bhn = b_hh[ecol + 256];
  const float vr = bvec[ecol], vz = bvec[ecol + 128], vn = bvec[ecol + 256];

  const int nstrip = N >> 4;
  const int G = (int)gridDim.x;
  int s = blockIdx.x;
  if (s >= nstrip) return;

  gather_strip_sorted(beg2, deg2s, orig2, csrc, hbc, s, w, lane, N,
                      AT[0][0], AT[0][1], degT[0], origT[0]);
  asm volatile("s_waitcnt lgkmcnt(0)" ::: "memory");
  __builtin_amdgcn_sched_barrier(0);
  __builtin_amdgcn_s_barrier();

  int cur = 0;
  while (true) {
    int ns = s + G;
    bool more = ns < nstrip;
    int nxt = (cur == 2) ? 0 : cur + 1;
    if (more)   // prefetch-gather next strip; writes only parity 'nxt'
      gather_strip_sorted(beg2, deg2s, orig2, csrc, hbc, ns, w, lane, N,
                          AT[nxt][0], AT[nxt][1], degT[nxt], origT[nxt]);
    // A-fragments from LDS (chunk-swizzled; <=2-way bank alias = free)
    B8u af[4];
#pragma unroll
    for (int kc = 0; kc < 4; ++kc)
      af[kc].u = *(const uint4*)(&AT[cur][gm][l16][(((quad + 4 * kc) ^ (l16 & 7)) * 8)]);
    f32x4 acc[3] = {};
#pragma unroll
    for (int kc = 0; kc < 4; ++kc)
#pragma unroll
      for (int g = 0; g < 3; ++g)
        acc[g] = __builtin_amdgcn_mfma_f32_16x16x32_bf16(af[kc].b, bfr[g][kc].b, acc[g], 0, 0, 0);
    // (a) all waves past prev epilogue's S/AT[cur] reads -> safe to write S
    __builtin_amdgcn_s_barrier();
#pragma unroll
    for (int g = 0; g < 3; ++g)
#pragma unroll
      for (int rg = 0; rg < 4; ++rg)
        S[gm * 3 + g][quad * 4 + rg][d0 + l16] = acc[g][rg];
    // (b) drain own LDS ops (S writes + gather writes), leave vmcnt in flight
    asm volatile("s_waitcnt lgkmcnt(0)" ::: "memory");
    __builtin_amdgcn_sched_barrier(0);
    __builtin_amdgcn_s_barrier();
    int n0 = s << 4;
#pragma unroll
    for (int k = 0; k < 2; ++k) {
      int row = erow0 + 8 * k;
      float dgf = (float)degT[cur][row];
      int og = origT[cur][row];
      int sc = (((ecol >> 3) ^ (row & 7)) * 8) + (ecol & 7);
      float hold = bf2f(AT[cur][1][row][sc]);
      float ir  = S[0][row][ecol] + dgf * vr + bir;
      float iz  = S[1][row][ecol] + dgf * vz + biz;
      float in_ = S[2][row][ecol] + dgf * vn + bin_;
      float hr  = S[3][row][ecol] + bhr;
      float hz  = S[4][row][ecol] + bhz;
      float hn  = S[5][row][ecol] + bhn;
      float r = __builtin_amdgcn_rcpf(1.f + __expf(-(ir + hr)));
      float z = __builtin_amdgcn_rcpf(1.f + __expf(-(iz + hz)));
      float x2 = in_ + r * hn;
      float e2 = __expf(2.f * x2);
      float nv = 1.f - 2.f * __builtin_amdgcn_rcpf(e2 + 1.f);   // tanh
      float hv = (1.f - z) * nv + z * hold;
      if (n0 + row < N)
        hbn[(size_t)og * HID + ecol] = f2bf(hv);
    }
    if (!more) break;
    s = ns; cur = nxt;
  }
}

// ---- per-graph counts from SORTED gid: binary search, no atomics
__global__ __launch_bounds__(64) void k_bounds(const int* __restrict__ gid,
                                               int* __restrict__ cnt, int N, int G) {
  int g = threadIdx.x;
  if (g >= G) return;
  int lo = 0, hi = N;
  while (lo < hi) { int mid = (lo + hi) >> 1; if (gid[mid] < g) lo = mid + 1; else hi = mid; }
  int lb0 = lo;
  lo = 0; hi = N;
  int g1 = g + 1;
  while (lo < hi) { int mid = (lo + hi) >> 1; if (gid[mid] < g1) lo = mid + 1; else hi = mid; }
  cnt[g] = lo - lb0;
}

// ---- pooling: graph_ids sorted -> run-length accumulate, few atomics
#define POOL_CHUNK 96
__global__ __launch_bounds__(128) void k_pool(const ushort* __restrict__ hb,
                                              const int* __restrict__ gid,
                                              float* __restrict__ hg, int N) {
  int d = threadIdx.x;
  int start = blockIdx.x * POOL_CHUNK;
  if (start >= N) return;
  int end = min(start + POOL_CHUNK, N);
  float acc = 0.f;
  int g = gid[start];
  for (int n = start; n < end; ++n) {
    int gn = gid[n];
    if (gn != g) { unsafeAtomicAdd(&hg[g * HID + d], acc); acc = 0.f; g = gn; }
    acc += fmaxf(bf2f(hb[(size_t)n * HID + d]), 0.f);   // relu
  }
  unsafeAtomicAdd(&hg[g * HID + d], acc);
}

__global__ __launch_bounds__(640) void k_cls(const float* __restrict__ hg,
                                             const int* __restrict__ cnt,
                                             const float* __restrict__ Wc,
                                             const float* __restrict__ bc,
                                             float* __restrict__ out, int G) {
  int t = threadIdx.x;
  if (t >= G * 10) return;
  int g = t / 10, c = t % 10;
  float inv = 1.f / fmaxf((float)cnt[g], 1.f);
  float acc = 0.f;
  for (int d = 0; d < HID; ++d) acc = fmaf(hg[g * HID + d], Wc[c * HID + d], acc);
  out[t] = acc * inv + bc[c];
}

extern "C" void kernel_launch(void* const* d_in, const int* in_sizes, int n_in,
                              void* d_out, int out_size, void* d_ws, size_t ws_size,
                              hipStream_t stream) {
  const int N = in_sizes[0];
  const int E = in_sizes[9];
  const float* m    = (const float*)d_in[0];
  const float* W_e  = (const float*)d_in[1];
  const float* b_e  = (const float*)d_in[2];
  const float* W_ih = (const float*)d_in[3];
  const float* b_ih = (const float*)d_in[4];
  const float* W_hh = (const float*)d_in[5];
  const float* b_hh = (const float*)d_in[6];
  const float* W_cls = (const float*)d_in[7];
  const float* b_cls = (const float*)d_in[8];
  const int* src = (const int*)d_in[9];
  const int* dst = (const int*)d_in[10];
  const int* gid = (const int*)d_in[11];
  const int G = out_size / 10;
  float* out = (float*)d_out;

  size_t off = 0;
  auto alloc = [&](size_t b) {
    char* p = (char*)d_ws + off;
    off += (b + 255) & ~(size_t)255;
    return (void*)p;
  };
  ushort* hb0    = (ushort*)alloc((size_t)N * HID * 2);
  ushort* hb1    = (ushort*)alloc((size_t)N * HID * 2);
  int*    deg    = (int*)   alloc((size_t)N * 4);
  int*    rowptr = (int*)   alloc((size_t)(N + 1) * 4);
  int*    csrc   = (int*)   alloc((size_t)E * 4);
  uint*   ebuf   = (uint*)  alloc((size_t)E * 4);
  int*    bhist  = (int*)   alloc((size_t)MAXBUK * 4);
  int*    bbase  = (int*)   alloc((size_t)(MAXBUK + 1) * 4);
  int*    gcur   = (int*)   alloc((size_t)MAXBUK * 4);
  ushort* Wcomb  = (ushort*)alloc((size_t)G3 * HID * 2);
  ushort* Whh16  = (ushort*)alloc((size_t)G3 * HID * 2);
  float*  bvec   = (float*) alloc((size_t)G3 * 4);
  float*  hg     = (float*) alloc((size_t)G * HID * 4);
  int*    cnt    = (int*)   alloc((size_t)G * 4);
  ushort* m16    = (ushort*)alloc((size_t)N * 2);
  ushort* hsum0  = (ushort*)alloc((size_t)N * 2);
  ushort* Wc0    = (ushort*)alloc((size_t)G3 * 2);
  ushort* Wh0    = (ushort*)alloc((size_t)G3 * 2);
  int*    dhist  = (int*)   alloc((size_t)DBUK * 4);
  int*    dcur   = (int*)   alloc((size_t)DBUK * 4);
  int*    orig2  = (int*)   alloc((size_t)N * 4);
  int*    beg2   = (int*)   alloc((size_t)N * 4);
  int*    deg2s  = (int*)   alloc((size_t)N * 4);
  if (off > ws_size) return;   // workspace too small -> visible failure

  const int NBUK = (N + BNODES - 1) >> BSHIFT;   // 196 at N=100k (<= MAXBUK)

  k_weights<<<2 * G3, HID, 0, stream>>>(W_e, b_e, W_ih, W_hh, Wcomb, Whh16, bvec, Wc0, Wh0);
  k_minit<<<(N + 255) / 256, 256, 0, stream>>>(m, m16, N);
  hipMemsetAsync(bhist, 0, (size_t)MAXBUK * 4, stream);
  k_bh<<<256, 256, 0, stream>>>(dst, bhist, E);
  k_bsc<<<1, MAXBUK, 0, stream>>>(bhist, bbase, gcur, rowptr, E, N);
  k_part<<<(E + PART_EPB - 1) / PART_EPB, 256, 0, stream>>>(src, dst, gcur, ebuf, E);
  k_fill2<<<NBUK, 256, 0, stream>>>(ebuf, bbase, csrc, rowptr, deg, N);

  // ---- degree-sort the node processing order (one-time, LDS-aggregated)
  hipMemsetAsync(dhist, 0, (size_t)DBUK * 4, stream);
  k_dhist<<<64, 256, 0, stream>>>(deg, dhist, N);
  k_dscan<<<1, 64, 0, stream>>>(dhist, dcur);
  k_dscatter<<<(N + 255) / 256, 256, 0, stream>>>(deg, rowptr, dcur, orig2, beg2, deg2s, N);

  // ---- step 0: h = [m,0,...,0] is rank-1 -> scalar gather + rank-1 GRU
  k_gather0<<<(N + 255) / 256, 256, 0, stream>>>(rowptr, csrc, m16, hsum0, N);
  k_gru0<<<(N * HID + 255) / 256, 256, 0, stream>>>(hsum0, m16, deg, Wc0, Wh0,
                                                    bvec, b_ih, b_hh, hb1, N);

  ushort* hbc = hb1;
  ushort* hbn = hb0;
  const int nstrip = N >> 4;
  const int fuse_blocks = nstrip < 256 ? nstrip : 256;   // 1 block/CU
  for (int s = 1; s < TSTEPS; ++s) {
    k_fused<<<fuse_blocks, 1024, 0, stream>>>(beg2, deg2s, orig2, csrc, hbc, hbn,
                                              Wcomb, Whh16, bvec, b_ih, b_hh, N);
    ushort* t = hbc; hbc = hbn; hbn = t;
  }

  hipMemsetAsync(hg, 0, (size_t)G * HID * 4, stream);
  k_bounds<<<1, 64, 0, stream>>>(gid, cnt, N, G);
  k_pool<<<(N + POOL_CHUNK - 1) / POOL_CHUNK, HID, 0, stream>>>(hbc, gid, hg, N);
  k_cls<<<1, 640, 0, stream>>>(hg, cnt, W_cls, b_cls, out, G);
}